// Round 3
// baseline (409.738 us; speedup 1.0000x reference)
//
#include <hip/hip_runtime.h>
#include <math.h>

constexpr int NPGc  = 128;     // nodes per graph (layer 1)
constexpr int NG    = 512;     // graphs
constexpr int EPGc  = 2048;    // edges per graph
constexpr int ETOT  = 1048576; // total edges
constexpr int IND   = 11;
constexpr int HIDc  = 32;
constexpr int FD    = 128;     // HEADS*HID
constexpr int K1c   = 103;
constexpr int K2c   = 83;
constexpr int NN    = NG * NPGc;
constexpr int N2c   = NG * K1c;

__device__ __forceinline__ float lrelu(float x){ return fmaxf(x, 0.2f*x); }

// order-preserving float<->uint for atomicMax
__device__ __forceinline__ unsigned flipF(float f){
    unsigned u = __float_as_uint(f);
    return u ^ (unsigned)(((int)u >> 31) | 0x80000000);
}
__device__ __forceinline__ float unflipF(unsigned u){
    unsigned m = ((u >> 31) - 1u) | 0x80000000u;
    return __uint_as_float(u ^ m);
}

// ---- fold attention vectors through Wg: Ws[k][h] = sum_j Wg[k][h*32+j]*av[h*32+j]
template<int KIN>
__device__ void foldDev(const float* __restrict__ Wg, const float* __restrict__ avs,
                        const float* __restrict__ avd, float* __restrict__ S, float* __restrict__ D, int t)
{
    if (t < KIN * 4) {
        int k = t >> 2, h = t & 3;
        float s = 0.f, d = 0.f;
        for (int j = 0; j < HIDc; j++) {
            float w = Wg[k*FD + h*HIDc + j];
            s = fmaf(w, avs[h*HIDc + j], s);
            d = fmaf(w, avd[h*HIDc + j], d);
        }
        S[t] = s; D[t] = d;
    }
}
__global__ void k_fold2(const float* W1, const float* s1, const float* d1, float* S1, float* D1,
                        const float* W2, const float* s2, const float* d2, float* S2, float* D2)
{
    if (blockIdx.x == 0) foldDev<IND>(W1, s1, d1, S1, D1, threadIdx.x);
    else                 foldDev<HIDc>(W2, s2, d2, S2, D2, threadIdx.x);
}

// ---- fused proj + GAT, one block per (graph, head) ----
template<int NNODE, int KIN, bool REMAP>
__global__ __launch_bounds__(256) void k_gat(
    const float* __restrict__ xin, const float* __restrict__ Wg,
    const float* __restrict__ WsS, const float* __restrict__ WsD,
    const int* __restrict__ ei, const int* __restrict__ rankv,
    const float* __restrict__ bias, float* __restrict__ outp)
{
    int g = blockIdx.x, h = blockIdx.y, t = threadIdx.x;
    __shared__ __align__(16) float xpL[NNODE * 36];   // padded rows: 9 float4 -> conflict-free gather
    __shared__ float wE[EPGc];
    __shared__ unsigned char bucket[EPGc];
    __shared__ float asL[NNODE], adL[NNODE], mLn[NNODE], selfW[NNODE], sDen[NNODE];
    __shared__ unsigned maxAsU[NNODE];
    __shared__ int cnt[128], offA[130], curA[128];
    __shared__ float WL[KIN * 32];
    __shared__ float WsSL[KIN], WsDL[KIN];
    __shared__ float bL[32];
    __shared__ signed char rmap[NPGc];

    // phase 0: weights + init
    for (int i = t; i < KIN * 32; i += 256) { int k = i >> 5, c = i & 31; WL[i] = Wg[k*FD + h*32 + c]; }
    if (t < KIN) { WsSL[t] = WsS[t*4 + h]; WsDL[t] = WsD[t*4 + h]; }
    if (t < 32) bL[t] = bias[h*32 + t];
    if (t < 128) cnt[t] = 0;
    if constexpr (REMAP) { if (t < NPGc) rmap[t] = (signed char)rankv[g*NPGc + t]; }
    __syncthreads();

    // phase 1: projection into LDS + attention dots (via folded vectors)
    for (int p = t; p < NNODE * 32; p += 256) {
        int n = p >> 5, c = p & 31;
        const float* xr = xin + (size_t)(g * NNODE + n) * KIN;
        float acc = 0.f;
        #pragma unroll
        for (int k = 0; k < KIN; k++) acc = fmaf(xr[k], WL[k*32 + c], acc);
        xpL[n*36 + c] = acc;
    }
    for (int n = t; n < NNODE; n += 256) {
        const float* xr = xin + (size_t)(g * NNODE + n) * KIN;
        float s = 0.f, d = 0.f;
        #pragma unroll
        for (int k = 0; k < KIN; k++) { float xv = xr[k]; s = fmaf(xv, WsSL[k], s); d = fmaf(xv, WsDL[k], d); }
        asL[n] = s; adL[n] = d; maxAsU[n] = flipF(s);   // self-loop seeds the max
    }
    __syncthreads();

    const int* dstG = ei + ETOT + g * EPGc;
    // phase 2: in-degree counts + exact per-dst max of as (lrelu is monotone)
    for (int e = t; e < EPGc; e += 256) {
        int dO = dstG[e] - g * NPGc, s0 = e >> 4;   // src is structural: e/16
        if constexpr (REMAP) {
            int sn = rmap[s0], dn = rmap[dO];
            if (sn >= 0 && dn >= 0) { atomicAdd(&cnt[dn], 1); atomicMax(&maxAsU[dn], flipF(asL[sn])); }
        } else {
            atomicAdd(&cnt[dO], 1); atomicMax(&maxAsU[dO], flipF(asL[s0]));
        }
    }
    __syncthreads();

    // phase 3: wave0 scans counts -> offsets; waves 1-2 compute m / self weight / denom seed
    if (t < 64) {
        int c0 = cnt[2*t], c1 = cnt[2*t + 1], ps = c0 + c1, P = ps;
        #pragma unroll
        for (int dlt = 1; dlt < 64; dlt <<= 1) { int v = __shfl_up(P, dlt); if (t >= dlt) P += v; }
        int E0 = P - ps;
        offA[2*t] = E0; offA[2*t + 1] = E0 + c0;
        curA[2*t] = E0; curA[2*t + 1] = E0 + c0;
        if (t == 63) offA[128] = P;
    } else if (t < 64 + NNODE) {
        int n = t - 64;
        float m = lrelu(unflipF(maxAsU[n]) + adL[n]);  // exact segment max
        mLn[n] = m;
        float ws = expf(lrelu(asL[n] + adL[n]) - m);
        selfW[n] = ws; sDen[n] = ws;
    }
    __syncthreads();

    // phase 4: edge-parallel exp weights, CSR scatter, denominator accumulate
    for (int e = t; e < EPGc; e += 256) {
        int dO = dstG[e] - g * NPGc, s0 = e >> 4;
        int sn, dn; bool ok;
        if constexpr (REMAP) { sn = rmap[s0]; dn = rmap[dO]; ok = (sn >= 0 && dn >= 0); }
        else                 { sn = s0; dn = dO; ok = true; }
        if (ok) {
            float w = expf(lrelu(asL[sn] + adL[dn]) - mLn[dn]);
            int pos = atomicAdd(&curA[dn], 1);
            bucket[pos] = (unsigned char)sn; wE[pos] = w;
            atomicAdd(&sDen[dn], w);
        }
    }
    __syncthreads();

    // phase 5: aggregation, all reads LDS, conflict-free via row pad 36
    const float4* X4 = (const float4*)xpL;
    for (int p = t; p < NNODE * 8; p += 256) {
        int n = p >> 3, c4 = p & 7;
        float w0 = selfW[n];
        float4 v = X4[n*9 + c4];
        float4 acc; acc.x = w0*v.x; acc.y = w0*v.y; acc.z = w0*v.z; acc.w = w0*v.w;
        int lo = offA[n], hi = offA[n + 1];
        for (int i = lo; i < hi; i++) {
            int sc = bucket[i]; float w = wE[i];
            float4 u = X4[sc*9 + c4];
            acc.x = fmaf(w, u.x, acc.x); acc.y = fmaf(w, u.y, acc.y);
            acc.z = fmaf(w, u.z, acc.z); acc.w = fmaf(w, u.w, acc.w);
        }
        float inv = 1.f / (sDen[n] + 1e-16f);
        float4 r;
        r.x = fmaxf(fmaf(acc.x, inv, bL[c4*4 + 0]), 0.f);
        r.y = fmaxf(fmaf(acc.y, inv, bL[c4*4 + 1]), 0.f);
        r.z = fmaxf(fmaf(acc.z, inv, bL[c4*4 + 2]), 0.f);
        r.w = fmaxf(fmaf(acc.w, inv, bL[c4*4 + 3]), 0.f);
        *(float4*)(outp + (size_t)(g * NNODE + n) * FD + h*32 + c4*4) = r;
    }
}

// ---- fused linear(128->32) + topk pool + readout, one graph per block ----
template<int NIN, int KEEP, bool FIRST>
__global__ __launch_bounds__(256) void k_linpool(
    const float* __restrict__ hg, const float* __restrict__ Wt, const float* __restrict__ bt,
    const float* __restrict__ pw, float* __restrict__ xnew, int* __restrict__ rankv,
    float* __restrict__ gfeat, const float* __restrict__ gprev)
{
    int g = blockIdx.x, t = threadIdx.x;
    __shared__ __align__(16) float hgT[NIN * 16];
    __shared__ float htL[NIN * 33];               // pad 33 breaks column-read conflicts
    __shared__ float scoreL[NIN], valL[NIN];
    __shared__ int rnkL[NIN];

    int j = t & 31, nb = t >> 5;                  // item: node = nb + r*8, channel j
    constexpr int RMAX = (NIN + 7) / 8;
    float acc[RMAX];
    float btj = bt[j];
    #pragma unroll
    for (int r = 0; r < RMAX; r++) acc[r] = btj;

    for (int kc = 0; kc < 8; kc++) {
        __syncthreads();
        for (int i = t; i < NIN * 4; i += 256) {
            int n = i >> 2, q = i & 3;
            ((float4*)hgT)[i] = *(const float4*)(hg + ((size_t)(g*NIN + n)*FD + kc*16 + q*4));
        }
        __syncthreads();
        float w[16];
        #pragma unroll
        for (int kk = 0; kk < 16; kk++) w[kk] = Wt[(kc*16 + kk)*HIDc + j];
        #pragma unroll
        for (int r = 0; r < RMAX; r++) {
            int n = nb + r*8; if (n >= NIN) break;
            const float4* hr = (const float4*)(hgT + n*16);
            float4 h0 = hr[0], h1 = hr[1], h2 = hr[2], h3 = hr[3];
            float a = acc[r];
            a = fmaf(h0.x, w[0],  a); a = fmaf(h0.y, w[1],  a); a = fmaf(h0.z, w[2],  a); a = fmaf(h0.w, w[3],  a);
            a = fmaf(h1.x, w[4],  a); a = fmaf(h1.y, w[5],  a); a = fmaf(h1.z, w[6],  a); a = fmaf(h1.w, w[7],  a);
            a = fmaf(h2.x, w[8],  a); a = fmaf(h2.y, w[9],  a); a = fmaf(h2.z, w[10], a); a = fmaf(h2.w, w[11], a);
            a = fmaf(h3.x, w[12], a); a = fmaf(h3.y, w[13], a); a = fmaf(h3.z, w[14], a); a = fmaf(h3.w, w[15], a);
            acc[r] = a;
        }
    }
    #pragma unroll
    for (int r = 0; r < RMAX; r++) { int n = nb + r*8; if (n < NIN) htL[n*33 + j] = acc[r]; }
    __syncthreads();

    // scores
    float nrm; { float ss = 0.f; for (int k = 0; k < HIDc; k++) { float w = pw[k]; ss = fmaf(w, w, ss); } nrm = sqrtf(ss); }
    if (t < NIN) {
        float dot = 0.f;
        for (int k = 0; k < HIDc; k++) dot = fmaf(htL[t*33 + k], pw[k], dot);
        float val = tanhf(dot / nrm);
        scoreL[t] = val; valL[t] = val;
    }
    __syncthreads();
    if (t < NIN) {
        float si = scoreL[t]; int rank = 0;
        for (int q = 0; q < NIN; q++) {
            float sj = scoreL[q];
            rank += (sj > si || (sj == si && q < t)) ? 1 : 0;
        }
        rnkL[t] = (rank < KEEP) ? rank : -1;
    }
    __syncthreads();
    if (FIRST && t < NIN) rankv[g*NPGc + t] = rnkL[t];
    if (FIRST) {
        for (int p = t; p < NIN * 32; p += 256) {
            int n = p >> 5, jj = p & 31;
            int rk = rnkL[n];
            if (rk >= 0) xnew[((size_t)g*KEEP + rk)*HIDc + jj] = htL[n*33 + jj] * valL[n];
        }
    }
    if (t < HIDc) {
        float mx = -INFINITY, sm = 0.f;
        for (int n = 0; n < NIN; n++) {
            if (rnkL[n] >= 0) { float v = htL[n*33 + t] * valL[n]; mx = fmaxf(mx, v); sm += v; }
        }
        float mean = sm / (float)KEEP;
        if (FIRST) {
            gfeat[(size_t)g*64 + t] = mx;
            gfeat[(size_t)g*64 + 32 + t] = mean;
        } else {
            gfeat[(size_t)g*64 + t]      = gprev[(size_t)g*64 + t] + mx;
            gfeat[(size_t)g*64 + 32 + t] = gprev[(size_t)g*64 + 32 + t] + mean;
        }
    }
}

// ---- MLP head: 4 graphs per block (amortize W2 reads), 64->256->1024->1 ----
__global__ __launch_bounds__(256) void k_mlp(const float* __restrict__ gsum,
    const float* __restrict__ W1, const float* __restrict__ b1,
    const float* __restrict__ W2, const float* __restrict__ b2,
    const float* __restrict__ W3, const float* __restrict__ b3,
    float* __restrict__ outp)
{
    int g0 = blockIdx.x * 4, t = threadIdx.x;
    __shared__ float gL[256];
    __shared__ float h1L[1024];
    __shared__ float4 red[256];
    gL[t] = gsum[(size_t)g0*64 + t];
    __syncthreads();
    float bv = b1[t];
    float a0 = bv, a1 = bv, a2 = bv, a3 = bv;
    #pragma unroll 4
    for (int k = 0; k < 64; k++) {
        float w = W1[k*256 + t];
        a0 = fmaf(gL[k], w, a0); a1 = fmaf(gL[64 + k], w, a1);
        a2 = fmaf(gL[128 + k], w, a2); a3 = fmaf(gL[192 + k], w, a3);
    }
    h1L[t] = fmaxf(a0, 0.f); h1L[256 + t] = fmaxf(a1, 0.f);
    h1L[512 + t] = fmaxf(a2, 0.f); h1L[768 + t] = fmaxf(a3, 0.f);
    __syncthreads();
    float p0 = 0.f, p1 = 0.f, p2 = 0.f, p3 = 0.f;
    for (int q = 0; q < 4; q++) {
        int o = t + q*256;
        float b2v = b2[o], w3 = W3[o];
        float c0 = b2v, c1 = b2v, c2 = b2v, c3 = b2v;
        const float* w2c = W2 + o;
        #pragma unroll 4
        for (int i = 0; i < 256; i++) {
            float w = w2c[(size_t)i * 1024];
            c0 = fmaf(h1L[i], w, c0); c1 = fmaf(h1L[256 + i], w, c1);
            c2 = fmaf(h1L[512 + i], w, c2); c3 = fmaf(h1L[768 + i], w, c3);
        }
        p0 = fmaf(fmaxf(c0, 0.f), w3, p0); p1 = fmaf(fmaxf(c1, 0.f), w3, p1);
        p2 = fmaf(fmaxf(c2, 0.f), w3, p2); p3 = fmaf(fmaxf(c3, 0.f), w3, p3);
    }
    red[t] = make_float4(p0, p1, p2, p3);
    __syncthreads();
    for (int s = 128; s > 0; s >>= 1) {
        if (t < s) { float4 a = red[t], b = red[t + s]; a.x += b.x; a.y += b.y; a.z += b.z; a.w += b.w; red[t] = a; }
        __syncthreads();
    }
    if (t == 0) {
        float4 r = red[0]; float bb = b3[0];
        outp[g0] = r.x + bb; outp[g0 + 1] = r.y + bb; outp[g0 + 2] = r.z + bb; outp[g0 + 3] = r.w + bb;
    }
}

extern "C" void kernel_launch(void* const* d_in, const int* in_sizes, int n_in,
                              void* d_out, int out_size, void* d_ws, size_t ws_size,
                              hipStream_t stream)
{
    const float* x    = (const float*)d_in[0];
    const int*   ei   = (const int*)  d_in[1];
    const float* W_g1 = (const float*)d_in[4];
    const float* as1w = (const float*)d_in[5];
    const float* ad1w = (const float*)d_in[6];
    const float* b_g1 = (const float*)d_in[7];
    const float* W_t1 = (const float*)d_in[8];
    const float* b_t1 = (const float*)d_in[9];
    const float* pw1  = (const float*)d_in[10];
    const float* W_g2 = (const float*)d_in[11];
    const float* as2w = (const float*)d_in[12];
    const float* ad2w = (const float*)d_in[13];
    const float* b_g2 = (const float*)d_in[14];
    const float* W_t2 = (const float*)d_in[15];
    const float* b_t2 = (const float*)d_in[16];
    const float* pw2  = (const float*)d_in[17];
    const float* W_l1 = (const float*)d_in[18];
    const float* b_l1 = (const float*)d_in[19];
    const float* W_l2 = (const float*)d_in[20];
    const float* b_l2 = (const float*)d_in[21];
    const float* W_l3 = (const float*)d_in[22];
    const float* b_l3 = (const float*)d_in[23];
    float* out = (float*)d_out;

    char* ws = (char*)d_ws;
    size_t off = 0;
    auto alloc = [&](size_t elems) -> float* {
        float* p = (float*)(ws + off);
        off += ((elems * 4 + 255) / 256) * 256;
        return p;
    };
    float* hg1  = alloc((size_t)NN * FD);
    float* hg2  = alloc((size_t)N2c * FD);
    float* x2   = alloc((size_t)N2c * HIDc);
    int*   rank1= (int*)alloc((size_t)NN);
    float* g1   = alloc((size_t)NG * 64);
    float* gsum = alloc((size_t)NG * 64);
    float* wsS1 = alloc(64);
    float* wsD1 = alloc(64);
    float* wsS2 = alloc(128);
    float* wsD2 = alloc(128);

    k_fold2<<<2, 128, 0, stream>>>(W_g1, as1w, ad1w, wsS1, wsD1,
                                   W_g2, as2w, ad2w, wsS2, wsD2);

    k_gat<NPGc, IND, false><<<dim3(NG, 4), 256, 0, stream>>>(
        x, W_g1, wsS1, wsD1, ei, nullptr, b_g1, hg1);
    k_linpool<NPGc, K1c, true><<<NG, 256, 0, stream>>>(
        hg1, W_t1, b_t1, pw1, x2, rank1, g1, nullptr);

    k_gat<K1c, HIDc, true><<<dim3(NG, 4), 256, 0, stream>>>(
        x2, W_g2, wsS2, wsD2, ei, rank1, b_g2, hg2);
    k_linpool<K1c, K2c, false><<<NG, 256, 0, stream>>>(
        hg2, W_t2, b_t2, pw2, nullptr, nullptr, gsum, g1);

    k_mlp<<<NG/4, 256, 0, stream>>>(gsum, W_l1, b_l1, W_l2, b_l2, W_l3, b_l3, out);
}

// Round 4
// 336.097 us; speedup vs baseline: 1.2191x; 1.2191x over previous
//
#include <hip/hip_runtime.h>
#include <math.h>

constexpr int NPGc  = 128;     // nodes per graph (layer 1)
constexpr int NG    = 512;     // graphs
constexpr int EPGc  = 2048;    // edges per graph
constexpr int ETOT  = 1048576; // total edges
constexpr int IND   = 11;
constexpr int HIDc  = 32;
constexpr int FD    = 128;     // HEADS*HID
constexpr int K1c   = 103;
constexpr int K2c   = 83;
constexpr int NN    = NG * NPGc;
constexpr int N2c   = NG * K1c;

__device__ __forceinline__ float lrelu(float x){ return fmaxf(x, 0.2f*x); }

// order-preserving float<->uint for atomicMax
__device__ __forceinline__ unsigned flipF(float f){
    unsigned u = __float_as_uint(f);
    return u ^ (unsigned)(((int)u >> 31) | 0x80000000);
}
__device__ __forceinline__ float unflipF(unsigned u){
    unsigned m = ((u >> 31) - 1u) | 0x80000000u;
    return __uint_as_float(u ^ m);
}

// ---- fold attention vectors through Wg: Ws[k][h] = sum_j Wg[k][h*32+j]*av[h*32+j]
template<int KIN>
__device__ void foldDev(const float* __restrict__ Wg, const float* __restrict__ avs,
                        const float* __restrict__ avd, float* __restrict__ S, float* __restrict__ D, int t)
{
    if (t < KIN * 4) {
        int k = t >> 2, h = t & 3;
        float s = 0.f, d = 0.f;
        for (int j = 0; j < HIDc; j++) {
            float w = Wg[k*FD + h*HIDc + j];
            s = fmaf(w, avs[h*HIDc + j], s);
            d = fmaf(w, avd[h*HIDc + j], d);
        }
        S[t] = s; D[t] = d;
    }
}
__global__ void k_fold2(const float* W1, const float* s1, const float* d1, float* S1, float* D1,
                        const float* W2, const float* s2, const float* d2, float* S2, float* D2)
{
    if (blockIdx.x == 0) foldDev<IND>(W1, s1, d1, S1, D1, threadIdx.x);
    else                 foldDev<HIDc>(W2, s2, d2, S2, D2, threadIdx.x);
}

// ---- fused proj + GAT, one block per (graph, head) ----
template<int NNODE, int KIN, bool REMAP>
__global__ __launch_bounds__(256) void k_gat(
    const float* __restrict__ xin, const float* __restrict__ Wg,
    const float* __restrict__ WsS, const float* __restrict__ WsD,
    const int* __restrict__ ei, const int* __restrict__ rankv,
    const float* __restrict__ bias, float* __restrict__ outp)
{
    int g = blockIdx.x, h = blockIdx.y, t = threadIdx.x;
    __shared__ __align__(16) float xpL[NNODE * 36];   // padded rows: 9 float4 -> conflict-free gather
    __shared__ float wE[EPGc];                        // phase<=1: aliased as x stage; phase>=4: edge weights
    __shared__ unsigned char bucket[EPGc];
    __shared__ float asL[NNODE], adL[NNODE], mLn[NNODE], selfW[NNODE], sDen[NNODE];
    __shared__ unsigned maxAsU[NNODE];
    __shared__ int cnt[128], offA[130], curA[128];
    __shared__ float WL[KIN * 32];
    __shared__ float WsSL[KIN], WsDL[KIN];
    __shared__ float bL[32];
    __shared__ signed char rmap[NPGc];

    constexpr bool STAGE = (NNODE * KIN <= EPGc);     // layer1: 128*11=1408 fits in wE alias
    float* xL = wE;

    // phase 0: weights + init (+ x staging for layer 1)
    for (int i = t; i < KIN * 32; i += 256) { int k = i >> 5, c = i & 31; WL[i] = Wg[k*FD + h*32 + c]; }
    if (t < KIN) { WsSL[t] = WsS[t*4 + h]; WsDL[t] = WsD[t*4 + h]; }
    if (t < 32) bL[t] = bias[h*32 + t];
    if (t < 128) cnt[t] = 0;
    if constexpr (REMAP) { if (t < NPGc) rmap[t] = (signed char)rankv[g*NPGc + t]; }
    if constexpr (STAGE) {
        const float* xg = xin + (size_t)g * NNODE * KIN;
        for (int i = t; i < NNODE * KIN; i += 256) xL[i] = xg[i];
    }
    __syncthreads();

    // phase 1: projection into LDS + attention dots (via folded vectors)
    for (int p = t; p < NNODE * 32; p += 256) {
        int n = p >> 5, c = p & 31;
        float acc = 0.f;
        if constexpr (STAGE) {
            const float* xr = xL + n * KIN;
            #pragma unroll
            for (int k = 0; k < KIN; k++) acc = fmaf(xr[k], WL[k*32 + c], acc);
        } else {
            const float* xr = xin + (size_t)(g * NNODE + n) * KIN;
            #pragma unroll
            for (int k = 0; k < KIN; k++) acc = fmaf(xr[k], WL[k*32 + c], acc);
        }
        xpL[n*36 + c] = acc;
    }
    for (int n = t; n < NNODE; n += 256) {
        float s = 0.f, d = 0.f;
        if constexpr (STAGE) {
            const float* xr = xL + n * KIN;
            #pragma unroll
            for (int k = 0; k < KIN; k++) { float xv = xr[k]; s = fmaf(xv, WsSL[k], s); d = fmaf(xv, WsDL[k], d); }
        } else {
            const float* xr = xin + (size_t)(g * NNODE + n) * KIN;
            #pragma unroll
            for (int k = 0; k < KIN; k++) { float xv = xr[k]; s = fmaf(xv, WsSL[k], s); d = fmaf(xv, WsDL[k], d); }
        }
        asL[n] = s; adL[n] = d; maxAsU[n] = flipF(s);   // self-loop seeds the max
    }
    __syncthreads();

    const int* dstG = ei + ETOT + g * EPGc;
    // phase 2: in-degree counts + exact per-dst max of as (lrelu is monotone)
    for (int e = t; e < EPGc; e += 256) {
        int dO = dstG[e] - g * NPGc, s0 = e >> 4;   // src is structural: e/16
        if constexpr (REMAP) {
            int sn = rmap[s0], dn = rmap[dO];
            if (sn >= 0 && dn >= 0) { atomicAdd(&cnt[dn], 1); atomicMax(&maxAsU[dn], flipF(asL[sn])); }
        } else {
            atomicAdd(&cnt[dO], 1); atomicMax(&maxAsU[dO], flipF(asL[s0]));
        }
    }
    __syncthreads();

    // phase 3: wave0 scans counts -> offsets; waves 1-2 compute m / self weight / denom seed
    if (t < 64) {
        int c0 = cnt[2*t], c1 = cnt[2*t + 1], ps = c0 + c1, P = ps;
        #pragma unroll
        for (int dlt = 1; dlt < 64; dlt <<= 1) { int v = __shfl_up(P, dlt); if (t >= dlt) P += v; }
        int E0 = P - ps;
        offA[2*t] = E0; offA[2*t + 1] = E0 + c0;
        curA[2*t] = E0; curA[2*t + 1] = E0 + c0;
        if (t == 63) offA[128] = P;
    } else if (t < 64 + NNODE) {
        int n = t - 64;
        float m = lrelu(unflipF(maxAsU[n]) + adL[n]);  // exact segment max
        mLn[n] = m;
        float ws = expf(lrelu(asL[n] + adL[n]) - m);
        selfW[n] = ws; sDen[n] = ws;
    }
    __syncthreads();

    // phase 4: edge-parallel exp weights, CSR scatter, denominator accumulate
    for (int e = t; e < EPGc; e += 256) {
        int dO = dstG[e] - g * NPGc, s0 = e >> 4;
        int sn, dn; bool ok;
        if constexpr (REMAP) { sn = rmap[s0]; dn = rmap[dO]; ok = (sn >= 0 && dn >= 0); }
        else                 { sn = s0; dn = dO; ok = true; }
        if (ok) {
            float w = expf(lrelu(asL[sn] + adL[dn]) - mLn[dn]);
            int pos = atomicAdd(&curA[dn], 1);
            bucket[pos] = (unsigned char)sn; wE[pos] = w;
            atomicAdd(&sDen[dn], w);
        }
    }
    __syncthreads();

    // phase 5: aggregation, all reads LDS, conflict-free via row pad 36
    const float4* X4 = (const float4*)xpL;
    for (int p = t; p < NNODE * 8; p += 256) {
        int n = p >> 3, c4 = p & 7;
        float w0 = selfW[n];
        float4 v = X4[n*9 + c4];
        float4 acc; acc.x = w0*v.x; acc.y = w0*v.y; acc.z = w0*v.z; acc.w = w0*v.w;
        int lo = offA[n], hi = offA[n + 1];
        for (int i = lo; i < hi; i++) {
            int sc = bucket[i]; float w = wE[i];
            float4 u = X4[sc*9 + c4];
            acc.x = fmaf(w, u.x, acc.x); acc.y = fmaf(w, u.y, acc.y);
            acc.z = fmaf(w, u.z, acc.z); acc.w = fmaf(w, u.w, acc.w);
        }
        float inv = 1.f / (sDen[n] + 1e-16f);
        float4 r;
        r.x = fmaxf(fmaf(acc.x, inv, bL[c4*4 + 0]), 0.f);
        r.y = fmaxf(fmaf(acc.y, inv, bL[c4*4 + 1]), 0.f);
        r.z = fmaxf(fmaf(acc.z, inv, bL[c4*4 + 2]), 0.f);
        r.w = fmaxf(fmaf(acc.w, inv, bL[c4*4 + 3]), 0.f);
        *(float4*)(outp + (size_t)(g * NNODE + n) * FD + h*32 + c4*4) = r;
    }
}

// ---- fused linear(128->32) + topk pool + readout, one graph per block ----
template<int NIN, int KEEP, bool FIRST>
__global__ __launch_bounds__(256) void k_linpool(
    const float* __restrict__ hg, const float* __restrict__ Wt, const float* __restrict__ bt,
    const float* __restrict__ pw, float* __restrict__ xnew, int* __restrict__ rankv,
    float* __restrict__ gfeat, const float* __restrict__ gprev)
{
    int g = blockIdx.x, t = threadIdx.x;
    __shared__ __align__(16) float hgT[NIN * 16];
    __shared__ float htL[NIN * 33];               // pad 33 breaks column-read conflicts
    __shared__ float scoreL[NIN], valL[NIN];
    __shared__ int rnkL[NIN];

    int j = t & 31, nb = t >> 5;                  // item: node = nb + r*8, channel j
    constexpr int RMAX = (NIN + 7) / 8;
    float acc[RMAX];
    float btj = bt[j];
    #pragma unroll
    for (int r = 0; r < RMAX; r++) acc[r] = btj;

    for (int kc = 0; kc < 8; kc++) {
        __syncthreads();
        for (int i = t; i < NIN * 4; i += 256) {
            int n = i >> 2, q = i & 3;
            ((float4*)hgT)[i] = *(const float4*)(hg + ((size_t)(g*NIN + n)*FD + kc*16 + q*4));
        }
        __syncthreads();
        float w[16];
        #pragma unroll
        for (int kk = 0; kk < 16; kk++) w[kk] = Wt[(kc*16 + kk)*HIDc + j];
        #pragma unroll
        for (int r = 0; r < RMAX; r++) {
            int n = nb + r*8; if (n >= NIN) break;
            const float4* hr = (const float4*)(hgT + n*16);
            float4 h0 = hr[0], h1 = hr[1], h2 = hr[2], h3 = hr[3];
            float a = acc[r];
            a = fmaf(h0.x, w[0],  a); a = fmaf(h0.y, w[1],  a); a = fmaf(h0.z, w[2],  a); a = fmaf(h0.w, w[3],  a);
            a = fmaf(h1.x, w[4],  a); a = fmaf(h1.y, w[5],  a); a = fmaf(h1.z, w[6],  a); a = fmaf(h1.w, w[7],  a);
            a = fmaf(h2.x, w[8],  a); a = fmaf(h2.y, w[9],  a); a = fmaf(h2.z, w[10], a); a = fmaf(h2.w, w[11], a);
            a = fmaf(h3.x, w[12], a); a = fmaf(h3.y, w[13], a); a = fmaf(h3.z, w[14], a); a = fmaf(h3.w, w[15], a);
            acc[r] = a;
        }
    }
    #pragma unroll
    for (int r = 0; r < RMAX; r++) { int n = nb + r*8; if (n < NIN) htL[n*33 + j] = acc[r]; }
    __syncthreads();

    // scores
    float nrm; { float ss = 0.f; for (int k = 0; k < HIDc; k++) { float w = pw[k]; ss = fmaf(w, w, ss); } nrm = sqrtf(ss); }
    if (t < NIN) {
        float dot = 0.f;
        for (int k = 0; k < HIDc; k++) dot = fmaf(htL[t*33 + k], pw[k], dot);
        float val = tanhf(dot / nrm);
        scoreL[t] = val; valL[t] = val;
    }
    __syncthreads();
    if (t < NIN) {
        float si = scoreL[t]; int rank = 0;
        for (int q = 0; q < NIN; q++) {
            float sj = scoreL[q];
            rank += (sj > si || (sj == si && q < t)) ? 1 : 0;
        }
        rnkL[t] = (rank < KEEP) ? rank : -1;
    }
    __syncthreads();
    if (FIRST && t < NIN) rankv[g*NPGc + t] = rnkL[t];
    if (FIRST) {
        for (int p = t; p < NIN * 32; p += 256) {
            int n = p >> 5, jj = p & 31;
            int rk = rnkL[n];
            if (rk >= 0) xnew[((size_t)g*KEEP + rk)*HIDc + jj] = htL[n*33 + jj] * valL[n];
        }
    }
    if (t < HIDc) {
        float mx = -INFINITY, sm = 0.f;
        for (int n = 0; n < NIN; n++) {
            if (rnkL[n] >= 0) { float v = htL[n*33 + t] * valL[n]; mx = fmaxf(mx, v); sm += v; }
        }
        float mean = sm / (float)KEEP;
        if (FIRST) {
            gfeat[(size_t)g*64 + t] = mx;
            gfeat[(size_t)g*64 + 32 + t] = mean;
        } else {
            gfeat[(size_t)g*64 + t]      = gprev[(size_t)g*64 + t] + mx;
            gfeat[(size_t)g*64 + 32 + t] = gprev[(size_t)g*64 + 32 + t] + mean;
        }
    }
}

// ---- MLP part A: block = (4 graphs, quarter of h2). Writes per-(g,q) partial dots.
__global__ __launch_bounds__(256) void k_mlpA(const float* __restrict__ gsum,
    const float* __restrict__ W1, const float* __restrict__ b1,
    const float* __restrict__ W2, const float* __restrict__ b2,
    const float* __restrict__ W3, float* __restrict__ part)
{
    int gb = blockIdx.x, q = blockIdx.y, t = threadIdx.x;
    int g0 = gb * 4;
    __shared__ float gL[256];
    __shared__ float h1L[1024];
    __shared__ float4 red[256];
    gL[t] = gsum[(size_t)g0*64 + t];
    __syncthreads();
    // h1 for 4 graphs (redundant across q blocks; trivial cost)
    float bv = b1[t];
    float a0 = bv, a1 = bv, a2 = bv, a3 = bv;
    #pragma unroll 4
    for (int k = 0; k < 64; k++) {
        float w = W1[k*256 + t];
        a0 = fmaf(gL[k], w, a0); a1 = fmaf(gL[64 + k], w, a1);
        a2 = fmaf(gL[128 + k], w, a2); a3 = fmaf(gL[192 + k], w, a3);
    }
    h1L[t] = fmaxf(a0, 0.f); h1L[256 + t] = fmaxf(a1, 0.f);
    h1L[512 + t] = fmaxf(a2, 0.f); h1L[768 + t] = fmaxf(a3, 0.f);
    __syncthreads();
    int o = q * 256 + t;
    float b2v = b2[o], w3 = W3[o];
    float c0 = b2v, c1 = b2v, c2 = b2v, c3 = b2v;
    const float* w2c = W2 + o;
    #pragma unroll 8
    for (int i = 0; i < 256; i++) {
        float w = w2c[(size_t)i * 1024];
        c0 = fmaf(h1L[i], w, c0); c1 = fmaf(h1L[256 + i], w, c1);
        c2 = fmaf(h1L[512 + i], w, c2); c3 = fmaf(h1L[768 + i], w, c3);
    }
    red[t] = make_float4(fmaxf(c0, 0.f)*w3, fmaxf(c1, 0.f)*w3, fmaxf(c2, 0.f)*w3, fmaxf(c3, 0.f)*w3);
    __syncthreads();
    for (int s = 128; s > 0; s >>= 1) {
        if (t < s) { float4 a = red[t], b = red[t + s]; a.x += b.x; a.y += b.y; a.z += b.z; a.w += b.w; red[t] = a; }
        __syncthreads();
    }
    if (t == 0) {
        float4 r = red[0];
        part[(size_t)(g0 + 0)*4 + q] = r.x;
        part[(size_t)(g0 + 1)*4 + q] = r.y;
        part[(size_t)(g0 + 2)*4 + q] = r.z;
        part[(size_t)(g0 + 3)*4 + q] = r.w;
    }
}

// ---- MLP part B: deterministic 4-way partial sum + bias ----
__global__ void k_mlpB(const float* __restrict__ part, const float* __restrict__ b3,
                       float* __restrict__ outp)
{
    int g = blockIdx.x * 256 + threadIdx.x;
    if (g < NG) {
        float4 p = ((const float4*)part)[g];
        outp[g] = ((p.x + p.y) + (p.z + p.w)) + b3[0];
    }
}

extern "C" void kernel_launch(void* const* d_in, const int* in_sizes, int n_in,
                              void* d_out, int out_size, void* d_ws, size_t ws_size,
                              hipStream_t stream)
{
    const float* x    = (const float*)d_in[0];
    const int*   ei   = (const int*)  d_in[1];
    const float* W_g1 = (const float*)d_in[4];
    const float* as1w = (const float*)d_in[5];
    const float* ad1w = (const float*)d_in[6];
    const float* b_g1 = (const float*)d_in[7];
    const float* W_t1 = (const float*)d_in[8];
    const float* b_t1 = (const float*)d_in[9];
    const float* pw1  = (const float*)d_in[10];
    const float* W_g2 = (const float*)d_in[11];
    const float* as2w = (const float*)d_in[12];
    const float* ad2w = (const float*)d_in[13];
    const float* b_g2 = (const float*)d_in[14];
    const float* W_t2 = (const float*)d_in[15];
    const float* b_t2 = (const float*)d_in[16];
    const float* pw2  = (const float*)d_in[17];
    const float* W_l1 = (const float*)d_in[18];
    const float* b_l1 = (const float*)d_in[19];
    const float* W_l2 = (const float*)d_in[20];
    const float* b_l2 = (const float*)d_in[21];
    const float* W_l3 = (const float*)d_in[22];
    const float* b_l3 = (const float*)d_in[23];
    float* out = (float*)d_out;

    char* ws = (char*)d_ws;
    size_t off = 0;
    auto alloc = [&](size_t elems) -> float* {
        float* p = (float*)(ws + off);
        off += ((elems * 4 + 255) / 256) * 256;
        return p;
    };
    float* hg1  = alloc((size_t)NN * FD);
    float* hg2  = alloc((size_t)N2c * FD);
    float* x2   = alloc((size_t)N2c * HIDc);
    int*   rank1= (int*)alloc((size_t)NN);
    float* g1   = alloc((size_t)NG * 64);
    float* gsum = alloc((size_t)NG * 64);
    float* part = alloc((size_t)NG * 4);
    float* wsS1 = alloc(64);
    float* wsD1 = alloc(64);
    float* wsS2 = alloc(128);
    float* wsD2 = alloc(128);

    k_fold2<<<2, 128, 0, stream>>>(W_g1, as1w, ad1w, wsS1, wsD1,
                                   W_g2, as2w, ad2w, wsS2, wsD2);

    k_gat<NPGc, IND, false><<<dim3(NG, 4), 256, 0, stream>>>(
        x, W_g1, wsS1, wsD1, ei, nullptr, b_g1, hg1);
    k_linpool<NPGc, K1c, true><<<NG, 256, 0, stream>>>(
        hg1, W_t1, b_t1, pw1, x2, rank1, g1, nullptr);

    k_gat<K1c, HIDc, true><<<dim3(NG, 4), 256, 0, stream>>>(
        x2, W_g2, wsS2, wsD2, ei, rank1, b_g2, hg2);
    k_linpool<K1c, K2c, false><<<NG, 256, 0, stream>>>(
        hg2, W_t2, b_t2, pw2, nullptr, nullptr, gsum, g1);

    k_mlpA<<<dim3(NG/4, 4), 256, 0, stream>>>(gsum, W_l1, b_l1, W_l2, b_l2, W_l3, part);
    k_mlpB<<<2, 256, 0, stream>>>(part, b_l3, out);
}